// Round 2
// baseline (119.074 us; speedup 1.0000x reference)
//
#include <hip/hip_runtime.h>

#define N_SAMP 1024
#define XD     128
#define HID    256

// ---------------------------------------------------------------------------
// Workspace layout (float indices):
//   [0, 1024)            S       per-i sum of exp(T1[i,j]) over j
//   [1024]               T0sum   sum over i of T1[i,i]  (diagonal == T0 - b2)
//   [2048, 2048+256K)    xpb     x @ W1x + b1   (1024 x 256)
//   [next 256K)          yp      y @ W1y        (1024 x 256)
// ---------------------------------------------------------------------------

// Kernel 1: the two small GEMMs (134 MFLOP total — ~2-3 us, L2-bound on W1).
__global__ __launch_bounds__(256) void gemm_xy(
    const float* __restrict__ x, const float* __restrict__ y,
    const float* __restrict__ W1, const float* __restrict__ b1,
    float* __restrict__ xpb, float* __restrict__ yp)
{
    const int k  = threadIdx.x;        // hidden unit 0..255
    const int r0 = blockIdx.x * 4;     // 4 rows per block

    float ax0 = 0.f, ax1 = 0.f, ax2 = 0.f, ax3 = 0.f;
    float ay0 = 0.f, ay1 = 0.f, ay2 = 0.f, ay3 = 0.f;

    #pragma unroll 4
    for (int d = 0; d < XD; ++d) {
        const float wx = W1[d * HID + k];            // coalesced over k
        const float wy = W1[(XD + d) * HID + k];
        ax0 = fmaf(x[(r0 + 0) * XD + d], wx, ax0);   // uniform -> s_load
        ax1 = fmaf(x[(r0 + 1) * XD + d], wx, ax1);
        ax2 = fmaf(x[(r0 + 2) * XD + d], wx, ax2);
        ax3 = fmaf(x[(r0 + 3) * XD + d], wx, ax3);
        ay0 = fmaf(y[(r0 + 0) * XD + d], wy, ay0);
        ay1 = fmaf(y[(r0 + 1) * XD + d], wy, ay1);
        ay2 = fmaf(y[(r0 + 2) * XD + d], wy, ay2);
        ay3 = fmaf(y[(r0 + 3) * XD + d], wy, ay3);
    }

    const float bk = b1[k];
    xpb[(r0 + 0) * HID + k] = ax0 + bk;
    xpb[(r0 + 1) * HID + k] = ax1 + bk;
    xpb[(r0 + 2) * HID + k] = ax2 + bk;
    xpb[(r0 + 3) * HID + k] = ax3 + bk;
    yp [(r0 + 0) * HID + k] = ay0;
    yp [(r0 + 1) * HID + k] = ay1;
    yp [(r0 + 2) * HID + k] = ay2;
    yp [(r0 + 3) * HID + k] = ay3;
}

// Kernel 2: pairwise relu-dot + exp row-sums, wave-row structure.
//   block = 4 waves = 32 i-rows x 64 j-cols; wave = 8 i x 64 j; lane <-> j.
//   y-rows + W2 are wave-uniform -> s_load (scalar pipe, no VALU/LDS cost).
//   x-tile staged once in LDS; 1 ds_read_b128 feeds 96 VALU ops (8i x 4k x 3).
//   Grid 16x32 = 512 blocks = exactly 2 blocks/CU (LDS 66.6 KB -> 2 fit).
#define XSTR 260   // 64*260*4 B = 66.6 KB; multiple of 4 (16B-aligned rows),
                   // stride%8==4 spreads row-start banks across all 8 groups
__global__ __launch_bounds__(256, 2) void pair_lse(
    const float* __restrict__ yp, const float* __restrict__ xpb,
    const float* __restrict__ W2,
    float* __restrict__ S, float* __restrict__ T0sum)
{
    __shared__ float xs[64 * XSTR];

    const int tid = threadIdx.x;
    const int bj  = blockIdx.x;   // 64 j-cols
    const int bi  = blockIdx.y;   // 32 i-rows

    // Stage the 64x256 x-tile, float4-coalesced (16 iters x 16 B per thread).
    for (int idx = tid * 4; idx < 64 * 256; idx += 1024) {
        const int r = idx >> 8, c = idx & 255;
        *(float4*)&xs[r * XSTR + c] = *(const float4*)&xpb[(bj * 64 + r) * HID + c];
    }
    __syncthreads();

    const int wv   = __builtin_amdgcn_readfirstlane(tid >> 6); // wave id 0..3
    const int lane = tid & 63;                                 // j within tile
    const int i0   = bi * 32 + wv * 8;                         // first i-row
    const float* __restrict__ yb   = yp + i0 * HID;            // uniform base
    const float* __restrict__ xrow = &xs[lane * XSTR];

    float acc[8];
    #pragma unroll
    for (int ii = 0; ii < 8; ++ii) acc[ii] = 0.f;

    #pragma unroll 2
    for (int c = 0; c < HID; c += 4) {
        const float4 xv = *(const float4*)&xrow[c];        // LDS, per-lane
        const float4 w  = *(const float4*)&W2[c];          // uniform -> s_load
        float4 yv[8];
        #pragma unroll
        for (int ii = 0; ii < 8; ++ii)
            yv[ii] = *(const float4*)&yb[ii * HID + c];    // uniform -> s_load
        #pragma unroll
        for (int ii = 0; ii < 8; ++ii) {
            acc[ii] = fmaf(fmaxf(yv[ii].x + xv.x, 0.f), w.x, acc[ii]);
            acc[ii] = fmaf(fmaxf(yv[ii].y + xv.y, 0.f), w.y, acc[ii]);
            acc[ii] = fmaf(fmaxf(yv[ii].z + xv.z, 0.f), w.z, acc[ii]);
            acc[ii] = fmaf(fmaxf(yv[ii].w + xv.w, 0.f), w.w, acc[ii]);
        }
    }

    // Row-sums of exp over this wave's 64 j's: full-wave butterfly per i.
    // |acc| ~ O(1) so exp without max-shift is safe in f32.
    float ex[8];
    #pragma unroll
    for (int ii = 0; ii < 8; ++ii) {
        float e = __expf(acc[ii]);
        #pragma unroll
        for (int off = 32; off; off >>= 1) e += __shfl_xor(e, off, 64);
        ex[ii] = e;
    }
    if (lane == 0) {
        #pragma unroll
        for (int ii = 0; ii < 8; ++ii) atomicAdd(&S[i0 + ii], ex[ii]);
    }

    // Diagonal (T0): i_global == j_global only in blocks with bj == bi>>1.
    if (bj == (bi >> 1)) {
        float dv = 0.f;
        #pragma unroll
        for (int ii = 0; ii < 8; ++ii)
            if (i0 + ii - bj * 64 == lane) dv += acc[ii];
        #pragma unroll
        for (int off = 32; off; off >>= 1) dv += __shfl_xor(dv, off, 64);
        if (lane == 0) atomicAdd(T0sum, dv);
    }
}

// Kernel 3: lse[i] = log(S[i]); combine means. Single block.
__global__ __launch_bounds__(256) void finalize(
    const float* __restrict__ S, const float* __restrict__ T0sum,
    const float* __restrict__ b2, float* __restrict__ out)
{
    __shared__ float red[4];
    const int tid = threadIdx.x;

    float ls = 0.f;
    for (int i = tid; i < N_SAMP; i += 256) ls += logf(S[i]);
    #pragma unroll
    for (int off = 32; off; off >>= 1) ls += __shfl_xor(ls, off, 64);
    if ((tid & 63) == 0) red[tid >> 6] = ls;
    __syncthreads();

    if (tid == 0) {
        const float lse_sum = red[0] + red[1] + red[2] + red[3];
        const float t0_mean  = T0sum[0] / (float)N_SAMP + b2[0];
        const float lse_mean = lse_sum / (float)N_SAMP + b2[0] - logf((float)N_SAMP);
        out[0] = t0_mean - lse_mean;
    }
}

extern "C" void kernel_launch(void* const* d_in, const int* in_sizes, int n_in,
                              void* d_out, int out_size, void* d_ws, size_t ws_size,
                              hipStream_t stream)
{
    const float* x  = (const float*)d_in[0];
    const float* y  = (const float*)d_in[1];
    const float* W1 = (const float*)d_in[2];
    const float* b1 = (const float*)d_in[3];
    const float* W2 = (const float*)d_in[4];
    const float* b2 = (const float*)d_in[5];

    float* ws   = (float*)d_ws;
    float* S    = ws;                          // 1024 floats
    float* T0s  = ws + 1024;                   // 1 float
    float* xpb  = ws + 2048;                   // 1024*256
    float* yp   = ws + 2048 + N_SAMP * HID;    // 1024*256

    // Zero the accumulators (ws is re-poisoned to 0xAA before every launch).
    hipMemsetAsync(d_ws, 0, (1024 + 1) * sizeof(float), stream);

    gemm_xy <<<dim3(N_SAMP / 4), dim3(256), 0, stream>>>(x, y, W1, b1, xpb, yp);
    pair_lse<<<dim3(16, 32),     dim3(256), 0, stream>>>(yp, xpb, W2, S, T0s);
    finalize<<<dim3(1),          dim3(256), 0, stream>>>(S, T0s, b2, (float*)d_out);
}

// Round 3
// 116.113 us; speedup vs baseline: 1.0255x; 1.0255x over previous
//
#include <hip/hip_runtime.h>

#define N_SAMP 1024
#define XD     128
#define HID    256

// ---------------------------------------------------------------------------
// Workspace layout (float indices):
//   [0, 1024)            S       per-i sum of exp(T1[i,j]) over j
//   [1024]               T0sum   sum over i of T1[i,i]  (diagonal, sans b2)
//   [2048, 2048+256K)    xpbT    (x @ W1x + b1)^T   [HID][N]  (k-major)
//   [next 256K)          ypT     (y @ W1y)^T        [HID][N]  (k-major)
// S/T0sum are zeroed by gemm_xy (ws is poisoned 0xAA before every launch).
// ---------------------------------------------------------------------------

// Kernel 1: the two small GEMMs, writing TRANSPOSED outputs. Thread k owns
// hidden unit k for 4 consecutive rows -> in k-major layout those 4 results
// are contiguous: one float4 store per array. Also zeroes S/T0sum.
__global__ __launch_bounds__(256) void gemm_xy(
    const float* __restrict__ x, const float* __restrict__ y,
    const float* __restrict__ W1, const float* __restrict__ b1,
    float* __restrict__ xpbT, float* __restrict__ ypT,
    float* __restrict__ S, float* __restrict__ T0sum)
{
    const int k  = threadIdx.x;        // hidden unit 0..255
    const int r0 = blockIdx.x * 4;     // 4 rows per block

    // Zero accumulators (256 blocks x 4 = 1024 S entries; block 0: T0sum).
    if (threadIdx.x < 4) S[blockIdx.x * 4 + threadIdx.x] = 0.f;
    if (blockIdx.x == 0 && threadIdx.x == 4) T0sum[0] = 0.f;

    float ax0 = 0.f, ax1 = 0.f, ax2 = 0.f, ax3 = 0.f;
    float ay0 = 0.f, ay1 = 0.f, ay2 = 0.f, ay3 = 0.f;

    #pragma unroll 4
    for (int d = 0; d < XD; ++d) {
        const float wx = W1[d * HID + k];            // coalesced over k
        const float wy = W1[(XD + d) * HID + k];
        ax0 = fmaf(x[(r0 + 0) * XD + d], wx, ax0);   // uniform -> s_load
        ax1 = fmaf(x[(r0 + 1) * XD + d], wx, ax1);
        ax2 = fmaf(x[(r0 + 2) * XD + d], wx, ax2);
        ax3 = fmaf(x[(r0 + 3) * XD + d], wx, ax3);
        ay0 = fmaf(y[(r0 + 0) * XD + d], wy, ay0);
        ay1 = fmaf(y[(r0 + 1) * XD + d], wy, ay1);
        ay2 = fmaf(y[(r0 + 2) * XD + d], wy, ay2);
        ay3 = fmaf(y[(r0 + 3) * XD + d], wy, ay3);
    }

    const float bk = b1[k];
    float4 xs = make_float4(ax0 + bk, ax1 + bk, ax2 + bk, ax3 + bk);
    float4 ys = make_float4(ay0, ay1, ay2, ay3);
    *(float4*)&xpbT[k * N_SAMP + r0] = xs;   // 16B-aligned (r0 % 4 == 0)
    *(float4*)&ypT [k * N_SAMP + r0] = ys;
}

// Kernel 2: pairwise relu-dot + exp row-sums. Pure global/L1 reads, no LDS,
// no syncthreads. Block = 64 j-cols x 32 i-rows; thread = 4j x 2i = 8 accs.
// Per k: xT float4 (wave covers 256 contiguous B -> coalesced), yT float2
// (16-lane broadcast groups -> 64 B/wave), W2[k] uniform -> s_load.
// 24 VALU ops per 2 vmem instr; grid 16x32 = 512 blocks = 2 blocks/CU.
__global__ __launch_bounds__(256) void pair_lse(
    const float* __restrict__ ypT, const float* __restrict__ xpbT,
    const float* __restrict__ W2,
    float* __restrict__ S, float* __restrict__ T0sum)
{
    const int tid = threadIdx.x;
    const int tj  = tid & 15;          // j sub-block 0..15
    const int ti  = tid >> 4;          // i sub-block 0..15
    const int bj  = blockIdx.x;        // 16 tiles of 64 j
    const int bi  = blockIdx.y;        // 32 tiles of 32 i
    const int j0  = bj * 64 + tj * 4;
    const int i0  = bi * 32 + ti * 2;

    float acc[2][4];
    #pragma unroll
    for (int a = 0; a < 2; ++a)
        #pragma unroll
        for (int b = 0; b < 4; ++b) acc[a][b] = 0.f;

    #pragma unroll 4
    for (int k = 0; k < HID; ++k) {
        const float4 xv = *(const float4*)&xpbT[k * N_SAMP + j0];
        const float2 yv = *(const float2*)&ypT [k * N_SAMP + i0];
        const float  w  = W2[k];                       // uniform -> s_load
        acc[0][0] = fmaf(fmaxf(yv.x + xv.x, 0.f), w, acc[0][0]);
        acc[0][1] = fmaf(fmaxf(yv.x + xv.y, 0.f), w, acc[0][1]);
        acc[0][2] = fmaf(fmaxf(yv.x + xv.z, 0.f), w, acc[0][2]);
        acc[0][3] = fmaf(fmaxf(yv.x + xv.w, 0.f), w, acc[0][3]);
        acc[1][0] = fmaf(fmaxf(yv.y + xv.x, 0.f), w, acc[1][0]);
        acc[1][1] = fmaf(fmaxf(yv.y + xv.y, 0.f), w, acc[1][1]);
        acc[1][2] = fmaf(fmaxf(yv.y + xv.z, 0.f), w, acc[1][2]);
        acc[1][3] = fmaf(fmaxf(yv.y + xv.w, 0.f), w, acc[1][3]);
    }

    // Per-i sums of exp over this thread's 4 j's, then across the 16 tj
    // lanes (contiguous within a wave), then one atomic per i per block.
    // |acc| ~ O(1): exp without max-shift is safe in f32.
    #pragma unroll
    for (int a = 0; a < 2; ++a) {
        float e = __expf(acc[a][0]) + __expf(acc[a][1])
                + __expf(acc[a][2]) + __expf(acc[a][3]);
        #pragma unroll
        for (int off = 8; off; off >>= 1) e += __shfl_xor(e, off, 16);
        if (tj == 0) atomicAdd(&S[i0 + a], e);
    }

    // Diagonal (T0): this block touches i==j iff bj == bi>>1.
    if (bj == (bi >> 1)) {
        float dv = 0.f;
        #pragma unroll
        for (int a = 0; a < 2; ++a)
            #pragma unroll
            for (int b = 0; b < 4; ++b)
                if (i0 + a == j0 + b) dv += acc[a][b];
        #pragma unroll
        for (int off = 32; off; off >>= 1) dv += __shfl_xor(dv, off, 64);
        if ((tid & 63) == 0) atomicAdd(T0sum, dv);
    }
}

// Kernel 3: lse[i] = log(S[i]); combine means. Single block.
__global__ __launch_bounds__(256) void finalize(
    const float* __restrict__ S, const float* __restrict__ T0sum,
    const float* __restrict__ b2, float* __restrict__ out)
{
    __shared__ float red[4];
    const int tid = threadIdx.x;

    float ls = 0.f;
    for (int i = tid; i < N_SAMP; i += 256) ls += logf(S[i]);
    #pragma unroll
    for (int off = 32; off; off >>= 1) ls += __shfl_xor(ls, off, 64);
    if ((tid & 63) == 0) red[tid >> 6] = ls;
    __syncthreads();

    if (tid == 0) {
        const float lse_sum = red[0] + red[1] + red[2] + red[3];
        const float t0_mean  = T0sum[0] / (float)N_SAMP + b2[0];
        const float lse_mean = lse_sum / (float)N_SAMP + b2[0] - logf((float)N_SAMP);
        out[0] = t0_mean - lse_mean;
    }
}

extern "C" void kernel_launch(void* const* d_in, const int* in_sizes, int n_in,
                              void* d_out, int out_size, void* d_ws, size_t ws_size,
                              hipStream_t stream)
{
    const float* x  = (const float*)d_in[0];
    const float* y  = (const float*)d_in[1];
    const float* W1 = (const float*)d_in[2];
    const float* b1 = (const float*)d_in[3];
    const float* W2 = (const float*)d_in[4];
    const float* b2 = (const float*)d_in[5];

    float* ws   = (float*)d_ws;
    float* S    = ws;                          // 1024 floats
    float* T0s  = ws + 1024;                   // 1 float
    float* xpbT = ws + 2048;                   // [HID][N] = 256*1024
    float* ypT  = ws + 2048 + HID * N_SAMP;    // [HID][N]

    gemm_xy <<<dim3(N_SAMP / 4), dim3(256), 0, stream>>>(x, y, W1, b1,
                                                         xpbT, ypT, S, T0s);
    pair_lse<<<dim3(16, 32),     dim3(256), 0, stream>>>(ypT, xpbT, W2, S, T0s);
    finalize<<<dim3(1),          dim3(256), 0, stream>>>(S, T0s, b2, (float*)d_out);
}